// Round 6
// baseline (1183.379 us; speedup 1.0000x reference)
//
#include <hip/hip_runtime.h>

// RadarRnn1: 4-layer tanh RNN (B=512,S=1024,IN=64,H=32) + per-step FC + softmax over S.
// R6 = R5 with the type fix: AMDGCN builtins (cvt_pkrtz, fdot2) use
// __fp16 ext_vector_type(2), not _Float16. Theory unchanged: R4's 144
// weight-floats/lane overflowed 132 VGPRs -> AGPR spill traffic each tick;
// f16-packed weights + v_dot2 shrink to ~92 weight regs and 88 mul-ops/tick.

#define BB 512
#define SS 1024
#define INF 64
#define HH 32
#define LL 4

typedef __fp16 v2h __attribute__((ext_vector_type(2)));
typedef const __attribute__((address_space(1))) void* gptr_t;
typedef __attribute__((address_space(3))) void* lptr_t;

__device__ __forceinline__ v2h bch(unsigned u) { return __builtin_bit_cast(v2h, u); }
__device__ __forceinline__ unsigned bcu(v2h h) { return __builtin_bit_cast(unsigned, h); }

// v = v + dpp_mov(v, CTRL); bound_ctrl=1 -> out-of-range lanes contribute 0.
template <int CTRL>
__device__ __forceinline__ float dpp_add(float v) {
  int y = __builtin_amdgcn_update_dpp(0, __float_as_int(v), CTRL, 0xF, 0xF, true);
  return v + __int_as_float(y);
}
template <int CTRL>
__device__ __forceinline__ float dpp_mov(float v) {
  int y = __builtin_amdgcn_update_dpp(0, __float_as_int(v), CTRL, 0xF, 0xF, true);
  return __int_as_float(y);
}

// 16-half dot (one matrix k-half): w[8] packed pairs vs 8 LDS dwords (2 uint4).
__device__ __forceinline__ float dot16(const v2h* w, const uint4* p) {
  uint4 u0 = p[0], u1 = p[1];
  float a = 0.f, c = 0.f;
  a = __builtin_amdgcn_fdot2(w[0], bch(u0.x), a, false);
  c = __builtin_amdgcn_fdot2(w[1], bch(u0.y), c, false);
  a = __builtin_amdgcn_fdot2(w[2], bch(u0.z), a, false);
  c = __builtin_amdgcn_fdot2(w[3], bch(u0.w), c, false);
  a = __builtin_amdgcn_fdot2(w[4], bch(u1.x), a, false);
  c = __builtin_amdgcn_fdot2(w[5], bch(u1.y), c, false);
  a = __builtin_amdgcn_fdot2(w[6], bch(u1.z), a, false);
  c = __builtin_amdgcn_fdot2(w[7], bch(u1.w), c, false);
  return a + c;
}

__global__ __launch_bounds__(64) void rnn_kernel(
    const float* __restrict__ x, const float* __restrict__ h_state,
    const float* __restrict__ W_ih0, const float* __restrict__ W_ih_rest,
    const float* __restrict__ W_hh, const float* __restrict__ b_ih,
    const float* __restrict__ b_hh, const float* __restrict__ fc_w,
    const float* __restrict__ fc_b, float* __restrict__ out) {
  __shared__ int hbuf16[2][LL][16];  // [parity][layer][unit-pair] f16x2
  __shared__ float xring[8][INF];    // x slot ring, filled by global_load_lds
  __shared__ float lbuf[64];         // logit staging (flushed every 64 ticks)

  const int lane = threadIdx.x;  // 64
  const int b    = blockIdx.x;   // one batch element per wave
  const int ks   = lane & 1;     // k-split half
  const int h    = lane >> 1;    // output unit 0..31

  // ---------------- weights into registers ----------------
  float4 w0x[8];                  // L0 x-part, fp32 (exact): 32 regs
  v2h w0h[8], wi[3][8], wh[3][8]; // f16-packed h-matrices: 56 regs
  {
    const float4* p = (const float4*)(W_ih0 + h * INF + ks * 32);
#pragma unroll
    for (int j = 0; j < 8; ++j) w0x[j] = p[j];
    const float2* q = (const float2*)(W_hh + h * HH + ks * 16);
#pragma unroll
    for (int j = 0; j < 8; ++j) w0h[j] = __builtin_amdgcn_cvt_pkrtz(q[j].x, q[j].y);
#pragma unroll
    for (int l = 1; l < LL; ++l) {
      const float2* pi = (const float2*)(W_ih_rest + ((l - 1) * HH + h) * HH + ks * 16);
      const float2* ph = (const float2*)(W_hh + (l * HH + h) * HH + ks * 16);
#pragma unroll
      for (int j = 0; j < 8; ++j) {
        wi[l - 1][j] = __builtin_amdgcn_cvt_pkrtz(pi[j].x, pi[j].y);
        wh[l - 1][j] = __builtin_amdgcn_cvt_pkrtz(ph[j].x, ph[j].y);
      }
    }
  }
  float bias[LL];
#pragma unroll
  for (int l = 0; l < LL; ++l) bias[l] = b_ih[l * HH + h] + b_hh[l * HH + h];
  const float fcwh = fc_w[h] * 0.5f;  // both ks lanes hold hval -> 64-lane sum is 2x
  const float fcb  = fc_b[0];

  // initial hidden state -> parity 1 (first read parity for every layer), f16-packed
  if (lane < 16) {
#pragma unroll
    for (int l = 0; l < LL; ++l) {
      float a = h_state[(l * BB + b) * HH + 2 * lane];
      float c = h_state[(l * BB + b) * HH + 2 * lane + 1];
      hbuf16[1][l][lane] = bcu(__builtin_amdgcn_cvt_pkrtz(a, c));
    }
  }
  // single wave: DS ops are in-order, no barrier needed anywhere.

  const float* xb = x + (size_t)b * SS * INF;
#pragma unroll
  for (int j = 0; j < 6; ++j)  // prefill: 6 in-flight global_load_lds
    __builtin_amdgcn_global_load_lds((gptr_t)(xb + j * INF + lane),
                                     (lptr_t)&xring[j][0], 4, 0, 0);

  float* const outrow = out + (size_t)b * SS;
  float* const hfin   = out + (size_t)BB * SS;

  // tanh(a) without library call
  auto tanh_f = [](float a) __attribute__((always_inline)) {
    const float e = __expf(2.0f * a);
    return 1.0f - 2.0f / (e + 1.0f);
  };
  // pack own hv with neighbor-unit hv (quad_perm [2,3,2,3]) and store by 16 lanes
  auto store_h = [&](int par, int l, float hv) __attribute__((always_inline)) {
    float partner = dpp_mov<0xEE>(hv);  // lane 4u+i <- lane 4u+2+(i&1)
    if ((lane & 3) == 0)
      hbuf16[par][l][lane >> 2] = (int)bcu(__builtin_amdgcn_cvt_pkrtz(hv, partner));
  };

  // Parities (par = T&1) copied from R4 (verified): A0 w->[par][0] r<-[par^1][0];
  // A1 in<-[par^1][0] own<-[par][1] w->[par^1][1]; A2 in<-[par][1] own<-[par^1][2]
  // w->[par][2]; A3 in<-[par^1][2] own<-[par][3] w->[par^1][3].
  auto tick = [&](int T, int par, bool A0, bool A1, bool A2, bool A3)
      __attribute__((always_inline)) {
    if (A0) {
      // oldest of 6 in-flight x loads = slot T&7
      asm volatile("s_waitcnt vmcnt(5)" ::: "memory");
    }
    if (T < SS) {  // keep exactly one new load per active tick (clamped dup at tail)
      int tl = T + 6; tl = (tl < SS) ? tl : (SS - 1);
      __builtin_amdgcn_global_load_lds((gptr_t)(xb + tl * INF + lane),
                                       (lptr_t)&xring[(T + 6) & 7][0], 4, 0, 0);
    }
    if (A0) {
      const float4* xs = (const float4*)&xring[T & 7][ks * 32];
      float a0 = 0.f, a1 = 0.f, a2 = 0.f, a3 = 0.f;
#pragma unroll
      for (int j = 0; j < 8; ++j) {
        float4 xv = xs[j];
        a0 += w0x[j].x * xv.x; a1 += w0x[j].y * xv.y;
        a2 += w0x[j].z * xv.z; a3 += w0x[j].w * xv.w;
      }
      float acc = ((a0 + a1) + (a2 + a3))
                + dot16(w0h, (const uint4*)&hbuf16[par ^ 1][0][ks * 8]);
      acc = dpp_add<0xB1>(acc) + bias[0];
      const float hv = tanh_f(acc);
      store_h(par, 0, hv);
      if (T == SS - 1 && ks == 0) hfin[(0 * BB + b) * HH + h] = hv;
    }
    if (A1) {
      float acc = dot16(wi[0], (const uint4*)&hbuf16[par ^ 1][0][ks * 8])
                + dot16(wh[0], (const uint4*)&hbuf16[par][1][ks * 8]);
      acc = dpp_add<0xB1>(acc) + bias[1];
      const float hv = tanh_f(acc);
      store_h(par ^ 1, 1, hv);
      if (T - 1 == SS - 1 && ks == 0) hfin[(1 * BB + b) * HH + h] = hv;
    }
    if (A2) {
      float acc = dot16(wi[1], (const uint4*)&hbuf16[par][1][ks * 8])
                + dot16(wh[1], (const uint4*)&hbuf16[par ^ 1][2][ks * 8]);
      acc = dpp_add<0xB1>(acc) + bias[2];
      const float hv = tanh_f(acc);
      store_h(par, 2, hv);
      if (T - 2 == SS - 1 && ks == 0) hfin[(2 * BB + b) * HH + h] = hv;
    }
    if (A3) {
      float acc = dot16(wi[2], (const uint4*)&hbuf16[par ^ 1][2][ks * 8])
                + dot16(wh[2], (const uint4*)&hbuf16[par][3][ks * 8]);
      acc = dpp_add<0xB1>(acc) + bias[3];
      const float hv = tanh_f(acc);
      store_h(par ^ 1, 3, hv);
      const int t3 = T - 3;
      if (t3 == SS - 1 && ks == 0) hfin[(3 * BB + b) * HH + h] = hv;
      // FC: DPP cascade (lane 63 ends with the 64-lane sum), stage in LDS.
      float v = hv * fcwh;
      v = dpp_add<0x111>(v);  // row_shr:1
      v = dpp_add<0x112>(v);  // row_shr:2
      v = dpp_add<0x114>(v);  // row_shr:4
      v = dpp_add<0x118>(v);  // row_shr:8
      v = dpp_add<0x142>(v);  // row_bcast:15
      v = dpp_add<0x143>(v);  // row_bcast:31
      if (lane == 63) lbuf[t3 & 63] = v + fcb;
      if ((t3 & 63) == 63) {  // coalesced flush of 64 logits
        float lv = lbuf[lane];
        outrow[t3 - 63 + lane] = lv;
      }
    }
  };

  // prologue (layers come online one per tick)
  tick(0, 0, true, false, false, false);
  tick(1, 1, true, true, false, false);
  tick(2, 0, true, true, true, false);
  tick(3, 1, true, true, true, true);
  // steady: T = 4 .. SS-1 (1020 ticks, even), parity compile-time via unroll-2
  for (int T = 4; T < SS; T += 2) {
    tick(T, 0, true, true, true, true);
    tick(T + 1, 1, true, true, true, true);
  }
  // drain
  tick(SS, 0, false, true, true, true);
  tick(SS + 1, 1, false, false, true, true);
  tick(SS + 2, 0, false, false, false, true);
}

__global__ __launch_bounds__(256) void softmax_kernel(float* __restrict__ out) {
  __shared__ float red[8];
  const int row = blockIdx.x;
  float* p = out + (size_t)row * SS;
  const int tid = threadIdx.x;
  float4 v = ((const float4*)p)[tid];  // 256 threads x 4 = 1024 logits
  float m = fmaxf(fmaxf(v.x, v.y), fmaxf(v.z, v.w));
#pragma unroll
  for (int d = 32; d >= 1; d >>= 1) m = fmaxf(m, __shfl_xor(m, d));
  if ((tid & 63) == 0) red[tid >> 6] = m;
  __syncthreads();
  m = fmaxf(fmaxf(red[0], red[1]), fmaxf(red[2], red[3]));
  const float e0 = __expf(v.x - m), e1 = __expf(v.y - m);
  const float e2 = __expf(v.z - m), e3 = __expf(v.w - m);
  float s = (e0 + e1) + (e2 + e3);
#pragma unroll
  for (int d = 32; d >= 1; d >>= 1) s += __shfl_xor(s, d);
  if ((tid & 63) == 0) red[4 + (tid >> 6)] = s;
  __syncthreads();
  s = (red[4] + red[5]) + (red[6] + red[7]);
  const float inv = 1.0f / s;
  float4 o;
  o.x = e0 * inv; o.y = e1 * inv; o.z = e2 * inv; o.w = e3 * inv;
  ((float4*)p)[tid] = o;
}

extern "C" void kernel_launch(void* const* d_in, const int* in_sizes, int n_in,
                              void* d_out, int out_size, void* d_ws, size_t ws_size,
                              hipStream_t stream) {
  const float* x         = (const float*)d_in[0];
  const float* h_state   = (const float*)d_in[1];
  const float* W_ih0     = (const float*)d_in[2];
  const float* W_ih_rest = (const float*)d_in[3];
  const float* W_hh      = (const float*)d_in[4];
  const float* b_ih      = (const float*)d_in[5];
  const float* b_hh      = (const float*)d_in[6];
  const float* fc_w      = (const float*)d_in[7];
  const float* fc_b      = (const float*)d_in[8];
  float* out = (float*)d_out;

  hipLaunchKernelGGL(rnn_kernel, dim3(BB), dim3(64), 0, stream,
                     x, h_state, W_ih0, W_ih_rest, W_hh, b_ih, b_hh, fc_w, fc_b, out);
  hipLaunchKernelGGL(softmax_kernel, dim3(BB), dim3(256), 0, stream, out);
}

// Round 7
// 959.384 us; speedup vs baseline: 1.2335x; 1.2335x over previous
//
#include <hip/hip_runtime.h>

// RadarRnn1: 4-layer tanh RNN (B=512,S=1024,IN=64,H=32) + per-step FC + softmax over S.
// R7: the per-tick `asm volatile(s_waitcnt vmcnt :::"memory")` was a scheduling
// wall executed 1024x -- every tick's ds_reads (120cy) re-exposed serially
// (R6: fewer insts, MORE stall). Fix: precompute u0 = x@W_ih0^T + b0 in a
// separate memory-bound kernel (no recurrence dependence), stream u0 per-lane
// via plain register loads (distance-4, dependence-scheduled vmcnt, no asm,
// no global_load_lds, no clobbers), and read each h-vector once per tick
// (A_l own-state == A_{l+1} input: 4 vectors = 8 ds_read_b128, was 14).

#define BB 512
#define SS 1024
#define INF 64
#define HH 32
#define LL 4

typedef __fp16 v2h __attribute__((ext_vector_type(2)));

__device__ __forceinline__ v2h bch(unsigned u) { return __builtin_bit_cast(v2h, u); }
__device__ __forceinline__ unsigned bcu(v2h h) { return __builtin_bit_cast(unsigned, h); }

// v = v + dpp_mov(v, CTRL); bound_ctrl=1 -> out-of-range lanes contribute 0.
template <int CTRL>
__device__ __forceinline__ float dpp_add(float v) {
  int y = __builtin_amdgcn_update_dpp(0, __float_as_int(v), CTRL, 0xF, 0xF, true);
  return v + __int_as_float(y);
}
template <int CTRL>
__device__ __forceinline__ float dpp_mov(float v) {
  int y = __builtin_amdgcn_update_dpp(0, __float_as_int(v), CTRL, 0xF, 0xF, true);
  return __int_as_float(y);
}

// 16-half dot: w[8] packed f16 pairs against value-passed LDS data (read phase
// separated from compute so the scheduler can batch the ds_reads).
__device__ __forceinline__ float dot16v(const v2h* w, uint4 u0, uint4 u1) {
  float a = 0.f, c = 0.f;
  a = __builtin_amdgcn_fdot2(w[0], bch(u0.x), a, false);
  c = __builtin_amdgcn_fdot2(w[1], bch(u0.y), c, false);
  a = __builtin_amdgcn_fdot2(w[2], bch(u0.z), a, false);
  c = __builtin_amdgcn_fdot2(w[3], bch(u0.w), c, false);
  a = __builtin_amdgcn_fdot2(w[4], bch(u1.x), a, false);
  c = __builtin_amdgcn_fdot2(w[5], bch(u1.y), c, false);
  a = __builtin_amdgcn_fdot2(w[6], bch(u1.z), a, false);
  c = __builtin_amdgcn_fdot2(w[7], bch(u1.w), c, false);
  return a + c;
}

// ---------------- u0 = x @ W_ih0^T + (b_ih0 + b_hh0) ----------------
// Memory-bound pre-pass: 8192 waves x 64 rows. Lane (ks,h) holds W row-half in
// fp32 regs; x row read via broadcast dwordx4 (2 distinct 16B per inst -> each
// x byte fetched once per wave-exclusive row).
__global__ __launch_bounds__(256) void u0_kernel(
    const float* __restrict__ x, const float* __restrict__ W_ih0,
    const float* __restrict__ b_ih, const float* __restrict__ b_hh,
    float* __restrict__ u0) {
  const int lane = threadIdx.x & 63;
  const int wid  = blockIdx.x * 4 + (threadIdx.x >> 6);
  const int ks   = lane & 1;
  const int h    = lane >> 1;
  float4 w[8];
  const float4* wp = (const float4*)(W_ih0 + h * INF + ks * 32);
#pragma unroll
  for (int j = 0; j < 8; ++j) w[j] = wp[j];
  const float bias0 = b_ih[h] + b_hh[h];
  const int base = wid * 64;
#pragma unroll 2
  for (int r = 0; r < 64; ++r) {
    const int row = base + r;
    const float4* xr = (const float4*)(x + (size_t)row * INF + ks * 32);
    float a0 = 0.f, a1 = 0.f, a2 = 0.f, a3 = 0.f;
#pragma unroll
    for (int j = 0; j < 8; ++j) {
      float4 xv = xr[j];
      a0 += w[j].x * xv.x; a1 += w[j].y * xv.y;
      a2 += w[j].z * xv.z; a3 += w[j].w * xv.w;
    }
    float acc = (a0 + a1) + (a2 + a3);
    acc = dpp_add<0xB1>(acc) + bias0;
    if (ks == 0) u0[(size_t)row * HH + h] = acc;
  }
}

// ---------------- recurrent kernel: one wave per batch element ----------------
__global__ __launch_bounds__(64) void rnn_kernel(
    const float* __restrict__ u0g_all, const float* __restrict__ h_state,
    const float* __restrict__ W_ih_rest, const float* __restrict__ W_hh,
    const float* __restrict__ b_ih, const float* __restrict__ b_hh,
    const float* __restrict__ fc_w, const float* __restrict__ fc_b,
    float* __restrict__ out) {
  __shared__ int hbuf16[2][LL][16];  // [parity][layer][unit-pair] f16x2
  __shared__ float lbuf[64];         // logit staging (flushed every 64 ticks)

  const int lane = threadIdx.x;  // 64
  const int b    = blockIdx.x;   // one batch element per wave
  const int ks   = lane & 1;     // k-split half
  const int h    = lane >> 1;    // output unit 0..31

  // weights: f16-packed h-matrices only (x-part lives in u0 now): 56 regs
  v2h w0h[8], wi[3][8], wh[3][8];
  {
    const float2* q = (const float2*)(W_hh + h * HH + ks * 16);
#pragma unroll
    for (int j = 0; j < 8; ++j) w0h[j] = __builtin_amdgcn_cvt_pkrtz(q[j].x, q[j].y);
#pragma unroll
    for (int l = 1; l < LL; ++l) {
      const float2* pi = (const float2*)(W_ih_rest + ((l - 1) * HH + h) * HH + ks * 16);
      const float2* ph = (const float2*)(W_hh + (l * HH + h) * HH + ks * 16);
#pragma unroll
      for (int j = 0; j < 8; ++j) {
        wi[l - 1][j] = __builtin_amdgcn_cvt_pkrtz(pi[j].x, pi[j].y);
        wh[l - 1][j] = __builtin_amdgcn_cvt_pkrtz(ph[j].x, ph[j].y);
      }
    }
  }
  float bias[LL];  // bias[0] unused (folded into u0)
#pragma unroll
  for (int l = 1; l < LL; ++l) bias[l] = b_ih[l * HH + h] + b_hh[l * HH + h];
  const float fcwh = fc_w[h] * 0.5f;  // both ks lanes hold hval -> 64-lane sum is 2x
  const float fcb  = fc_b[0];

  // initial hidden state -> parity 1 (first read parity), f16-packed
  if (lane < 16) {
#pragma unroll
    for (int l = 0; l < LL; ++l) {
      float a = h_state[(l * BB + b) * HH + 2 * lane];
      float c = h_state[(l * BB + b) * HH + 2 * lane + 1];
      hbuf16[1][l][lane] = (int)bcu(__builtin_amdgcn_cvt_pkrtz(a, c));
    }
  }
  // single wave: DS ops are in-order, no barrier needed anywhere.

  const float* ug = u0g_all + (size_t)b * SS * HH;
  float ur[4];  // rotating u0 prefetch regs, distance 4, no shifts
#pragma unroll
  for (int i = 0; i < 4; ++i) ur[i] = ug[i * HH + h];

  float* const outrow = out + (size_t)b * SS;
  float* const hfin   = out + (size_t)BB * SS;

  auto tanh_f = [](float a) __attribute__((always_inline)) {
    const float e = __expf(2.0f * a);
    return 1.0f - 2.0f / (e + 1.0f);
  };
  // pack own hv with neighbor-unit hv (quad_perm [2,3,2,3]) and store by 16 lanes
  auto store_h = [&](int par, int l, float hv) __attribute__((always_inline)) {
    float partner = dpp_mov<0xEE>(hv);
    if ((lane & 3) == 0)
      hbuf16[par][l][lane >> 2] = (int)bcu(__builtin_amdgcn_cvt_pkrtz(hv, partner));
  };
  auto ld2 = [&](const int* p, uint4& A, uint4& B) __attribute__((always_inline)) {
    const uint4* q = (const uint4*)p;
    A = q[0]; B = q[1];
  };

  // Verified parity pattern (R4/R6): shared vectors per tick:
  // V0=hbuf[par^1][0] (A0 own + A1 in), V1=hbuf[par][1] (A1 own + A2 in),
  // V2=hbuf[par^1][2] (A2 own + A3 in), V3=hbuf[par][3] (A3 own).
  auto tick = [&](int T, int par, int URI, bool A0, bool A1, bool A2, bool A3)
      __attribute__((always_inline)) {
    uint4 V0a, V0b, V1a, V1b, V2a, V2b, V3a, V3b;
    // ---- read phase: all LDS reads batched up front ----
    if (A0 || A1) ld2(&hbuf16[par ^ 1][0][ks * 8], V0a, V0b);
    if (A1 || A2) ld2(&hbuf16[par][1][ks * 8], V1a, V1b);
    if (A2 || A3) ld2(&hbuf16[par ^ 1][2][ks * 8], V2a, V2b);
    if (A3)       ld2(&hbuf16[par][3][ks * 8], V3a, V3b);
    // ---- compute + write phase ----
    if (A0) {
      float acc = dot16v(w0h, V0a, V0b);
      acc = dpp_add<0xB1>(acc) + ur[URI];  // u0 includes x-part + full bias0
      const float hv = tanh_f(acc);
      store_h(par, 0, hv);
      if (T == SS - 1 && ks == 0) hfin[(0 * BB + b) * HH + h] = hv;
      int tl = T + 4; tl = (tl < SS) ? tl : (SS - 1);
      ur[URI] = ug[tl * HH + h];  // reload for T+4 (plain load, dep-scheduled)
    }
    if (A1) {
      float acc = dot16v(wi[0], V0a, V0b) + dot16v(wh[0], V1a, V1b);
      acc = dpp_add<0xB1>(acc) + bias[1];
      const float hv = tanh_f(acc);
      store_h(par ^ 1, 1, hv);
      if (T == SS && ks == 0) hfin[(1 * BB + b) * HH + h] = hv;
    }
    if (A2) {
      float acc = dot16v(wi[1], V1a, V1b) + dot16v(wh[1], V2a, V2b);
      acc = dpp_add<0xB1>(acc) + bias[2];
      const float hv = tanh_f(acc);
      store_h(par, 2, hv);
      if (T == SS + 1 && ks == 0) hfin[(2 * BB + b) * HH + h] = hv;
    }
    if (A3) {
      float acc = dot16v(wi[2], V2a, V2b) + dot16v(wh[2], V3a, V3b);
      acc = dpp_add<0xB1>(acc) + bias[3];
      const float hv = tanh_f(acc);
      store_h(par ^ 1, 3, hv);
      const int t3 = T - 3;
      if (t3 == SS - 1 && ks == 0) hfin[(3 * BB + b) * HH + h] = hv;
      // FC reduce via DPP cascade; lane 63 holds the 64-lane sum.
      float v = hv * fcwh;
      v = dpp_add<0x111>(v);  // row_shr:1
      v = dpp_add<0x112>(v);  // row_shr:2
      v = dpp_add<0x114>(v);  // row_shr:4
      v = dpp_add<0x118>(v);  // row_shr:8
      v = dpp_add<0x142>(v);  // row_bcast:15
      v = dpp_add<0x143>(v);  // row_bcast:31
      if (lane == 63) lbuf[t3 & 63] = v + fcb;
      if ((t3 & 63) == 63) {  // coalesced flush of 64 logits
        float lv = lbuf[lane];
        outrow[t3 - 63 + lane] = lv;
      }
    }
  };

  // prologue (layers come online one per tick); URI = T&3
  tick(0, 0, 0, true, false, false, false);
  tick(1, 1, 1, true, true, false, false);
  tick(2, 0, 2, true, true, true, false);
  tick(3, 1, 3, true, true, true, true);
  // steady: unroll-4 so parity AND prefetch-reg index are compile-time
  for (int T = 4; T < SS; T += 4) {
    tick(T,     0, 0, true, true, true, true);
    tick(T + 1, 1, 1, true, true, true, true);
    tick(T + 2, 0, 2, true, true, true, true);
    tick(T + 3, 1, 3, true, true, true, true);
  }
  // drain
  tick(SS,     0, 0, false, true, true, true);
  tick(SS + 1, 1, 1, false, false, true, true);
  tick(SS + 2, 0, 2, false, false, false, true);
}

__global__ __launch_bounds__(256) void softmax_kernel(float* __restrict__ out) {
  __shared__ float red[8];
  const int row = blockIdx.x;
  float* p = out + (size_t)row * SS;
  const int tid = threadIdx.x;
  float4 v = ((const float4*)p)[tid];  // 256 threads x 4 = 1024 logits
  float m = fmaxf(fmaxf(v.x, v.y), fmaxf(v.z, v.w));
#pragma unroll
  for (int d = 32; d >= 1; d >>= 1) m = fmaxf(m, __shfl_xor(m, d));
  if ((tid & 63) == 0) red[tid >> 6] = m;
  __syncthreads();
  m = fmaxf(fmaxf(red[0], red[1]), fmaxf(red[2], red[3]));
  const float e0 = __expf(v.x - m), e1 = __expf(v.y - m);
  const float e2 = __expf(v.z - m), e3 = __expf(v.w - m);
  float s = (e0 + e1) + (e2 + e3);
#pragma unroll
  for (int d = 32; d >= 1; d >>= 1) s += __shfl_xor(s, d);
  if ((tid & 63) == 0) red[4 + (tid >> 6)] = s;
  __syncthreads();
  s = (red[4] + red[5]) + (red[6] + red[7]);
  const float inv = 1.0f / s;
  float4 o;
  o.x = e0 * inv; o.y = e1 * inv; o.z = e2 * inv; o.w = e3 * inv;
  ((float4*)p)[tid] = o;
}

extern "C" void kernel_launch(void* const* d_in, const int* in_sizes, int n_in,
                              void* d_out, int out_size, void* d_ws, size_t ws_size,
                              hipStream_t stream) {
  const float* x         = (const float*)d_in[0];
  const float* h_state   = (const float*)d_in[1];
  const float* W_ih0     = (const float*)d_in[2];
  const float* W_ih_rest = (const float*)d_in[3];
  const float* W_hh      = (const float*)d_in[4];
  const float* b_ih      = (const float*)d_in[5];
  const float* b_hh      = (const float*)d_in[6];
  const float* fc_w      = (const float*)d_in[7];
  const float* fc_b      = (const float*)d_in[8];
  float* out = (float*)d_out;
  float* u0  = (float*)d_ws;  // [B,S,32] fp32 = 67 MB scratch

  hipLaunchKernelGGL(u0_kernel, dim3(2048), dim3(256), 0, stream,
                     x, W_ih0, b_ih, b_hh, u0);
  hipLaunchKernelGGL(rnn_kernel, dim3(BB), dim3(64), 0, stream,
                     u0, h_state, W_ih_rest, W_hh, b_ih, b_hh, fc_w, fc_b, out);
  hipLaunchKernelGGL(softmax_kernel, dim3(BB), dim3(256), 0, stream, out);
}

// Round 8
// 696.813 us; speedup vs baseline: 1.6983x; 1.3768x over previous
//
#include <hip/hip_runtime.h>

// RadarRnn1: 4-layer tanh RNN (B=512,S=1024,IN=64,H=32) + per-step FC + softmax over S.
// R8: three fixes on the R7 structure.
// 1) u0_kernel was TA-bound (broadcast 2-address loads, 512 VMEM insts/wave,
//    ~230us for a 30us-of-HBM job). Rewrite: thread-per-row, W in LDS
//    (true-broadcast ds_reads), coalesced-by-reuse x loads, contiguous stores.
// 2) rnn_kernel VGPR_Count=80 < ~90 live => compiler parked loop-invariant
//    weights in AGPRs (fdot2 can't read AGPR -> v_accvgpr_read churn each tick,
//    same signature as R4). __launch_bounds__(64,1) unlocks the full register
//    budget (1 wave/SIMD needs no occupancy squeeze).
// 3) tanh used IEEE divide (no fast-math: div_scale/fmas/fixup ~10 insts x4/tick).
//    Use __builtin_amdgcn_rcpf + fma.

#define BB 512
#define SS 1024
#define INF 64
#define HH 32
#define LL 4

typedef __fp16 v2h __attribute__((ext_vector_type(2)));

__device__ __forceinline__ v2h bch(unsigned u) { return __builtin_bit_cast(v2h, u); }
__device__ __forceinline__ unsigned bcu(v2h h) { return __builtin_bit_cast(unsigned, h); }

// v = v + dpp_mov(v, CTRL); bound_ctrl=1 -> out-of-range lanes contribute 0.
template <int CTRL>
__device__ __forceinline__ float dpp_add(float v) {
  int y = __builtin_amdgcn_update_dpp(0, __float_as_int(v), CTRL, 0xF, 0xF, true);
  return v + __int_as_float(y);
}
template <int CTRL>
__device__ __forceinline__ float dpp_mov(float v) {
  int y = __builtin_amdgcn_update_dpp(0, __float_as_int(v), CTRL, 0xF, 0xF, true);
  return __int_as_float(y);
}

// tanh(a) = 1 - 2/(e^{2a}+1); e^{2a} = 2^(a * 2/ln2). v_exp + v_rcp + fma,
// no IEEE-div sequence. Saturates correctly (e->inf => 1, e->0 => -1).
__device__ __forceinline__ float tanh_fast(float a) {
  const float e = __builtin_amdgcn_exp2f(a * 2.885390081777927f);
  const float r = __builtin_amdgcn_rcpf(e + 1.0f);
  return __builtin_fmaf(-2.0f, r, 1.0f);
}

// 16-half dot: w[8] packed f16 pairs against value-passed LDS data.
__device__ __forceinline__ float dot16v(const v2h* w, uint4 u0, uint4 u1) {
  float a = 0.f, c = 0.f;
  a = __builtin_amdgcn_fdot2(w[0], bch(u0.x), a, false);
  c = __builtin_amdgcn_fdot2(w[1], bch(u0.y), c, false);
  a = __builtin_amdgcn_fdot2(w[2], bch(u0.z), a, false);
  c = __builtin_amdgcn_fdot2(w[3], bch(u0.w), c, false);
  a = __builtin_amdgcn_fdot2(w[4], bch(u1.x), a, false);
  c = __builtin_amdgcn_fdot2(w[5], bch(u1.y), c, false);
  a = __builtin_amdgcn_fdot2(w[6], bch(u1.z), a, false);
  c = __builtin_amdgcn_fdot2(w[7], bch(u1.w), c, false);
  return a + c;
}

// ---------------- u0 = x @ W_ih0^T + (b_ih0 + b_hh0) ----------------
// Thread-per-row GEMV: W (8KB) + bias staged in LDS once; per thread 16
// dwordx4 x-loads (each 64B line fully consumed across the kc loop) and one
// contiguous 128B output store. VALU-bound at ~14us, HBM floor ~21us.
__global__ __launch_bounds__(256) void u0_kernel(
    const float* __restrict__ x, const float* __restrict__ W_ih0,
    const float* __restrict__ b_ih, const float* __restrict__ b_hh,
    float* __restrict__ u0) {
  __shared__ float Wl[HH * INF];  // [u][k]
  __shared__ float bl[HH];
  const int tid = threadIdx.x;
  {
    const float4* src = (const float4*)W_ih0;
    float4* dst = (float4*)Wl;
    dst[tid] = src[tid];            // 256 x 16B = 4KB
    dst[tid + 256] = src[tid + 256];  // 8KB total
    if (tid < HH) bl[tid] = b_ih[tid] + b_hh[tid];
  }
  __syncthreads();

  const int row = blockIdx.x * 256 + tid;  // 2048 blocks x 256 rows
  const float4* xr = (const float4*)(x + (size_t)row * INF);
  float acc[HH];
#pragma unroll
  for (int u = 0; u < HH; ++u) acc[u] = bl[u];
#pragma unroll 4
  for (int kc = 0; kc < 16; ++kc) {
    const float4 xv = xr[kc];
#pragma unroll
    for (int u = 0; u < HH; ++u) {
      const float4 wv = ((const float4*)Wl)[u * 16 + kc];  // wave-broadcast
      acc[u] += wv.x * xv.x + wv.y * xv.y + wv.z * xv.z + wv.w * xv.w;
    }
  }
  float4* op = (float4*)(u0 + (size_t)row * HH);
#pragma unroll
  for (int j = 0; j < 8; ++j)
    op[j] = make_float4(acc[4 * j], acc[4 * j + 1], acc[4 * j + 2], acc[4 * j + 3]);
}

// ---------------- recurrent kernel: one wave per batch element ----------------
__global__ __launch_bounds__(64, 1) void rnn_kernel(
    const float* __restrict__ u0g_all, const float* __restrict__ h_state,
    const float* __restrict__ W_ih_rest, const float* __restrict__ W_hh,
    const float* __restrict__ b_ih, const float* __restrict__ b_hh,
    const float* __restrict__ fc_w, const float* __restrict__ fc_b,
    float* __restrict__ out) {
  __shared__ int hbuf16[2][LL][16];  // [parity][layer][unit-pair] f16x2
  __shared__ float lbuf[64];         // logit staging (flushed every 64 ticks)

  const int lane = threadIdx.x;  // 64
  const int b    = blockIdx.x;   // one batch element per wave
  const int ks   = lane & 1;     // k-split half
  const int h    = lane >> 1;    // output unit 0..31

  // weights: f16-packed h-matrices only (x-part lives in u0): 56 regs
  v2h w0h[8], wi[3][8], wh[3][8];
  {
    const float2* q = (const float2*)(W_hh + h * HH + ks * 16);
#pragma unroll
    for (int j = 0; j < 8; ++j) w0h[j] = __builtin_amdgcn_cvt_pkrtz(q[j].x, q[j].y);
#pragma unroll
    for (int l = 1; l < LL; ++l) {
      const float2* pi = (const float2*)(W_ih_rest + ((l - 1) * HH + h) * HH + ks * 16);
      const float2* ph = (const float2*)(W_hh + (l * HH + h) * HH + ks * 16);
#pragma unroll
      for (int j = 0; j < 8; ++j) {
        wi[l - 1][j] = __builtin_amdgcn_cvt_pkrtz(pi[j].x, pi[j].y);
        wh[l - 1][j] = __builtin_amdgcn_cvt_pkrtz(ph[j].x, ph[j].y);
      }
    }
  }
  float bias[LL];  // bias[0] unused (folded into u0)
#pragma unroll
  for (int l = 1; l < LL; ++l) bias[l] = b_ih[l * HH + h] + b_hh[l * HH + h];
  const float fcwh = fc_w[h] * 0.5f;  // both ks lanes hold hval -> 64-lane sum is 2x
  const float fcb  = fc_b[0];

  // initial hidden state -> parity 1 (first read parity), f16-packed
  if (lane < 16) {
#pragma unroll
    for (int l = 0; l < LL; ++l) {
      float a = h_state[(l * BB + b) * HH + 2 * lane];
      float c = h_state[(l * BB + b) * HH + 2 * lane + 1];
      hbuf16[1][l][lane] = (int)bcu(__builtin_amdgcn_cvt_pkrtz(a, c));
    }
  }
  // single wave: DS ops are in-order, no barrier needed anywhere.

  const float* ug = u0g_all + (size_t)b * SS * HH;
  float ur[4];  // rotating u0 prefetch regs, distance 4, no shifts
#pragma unroll
  for (int i = 0; i < 4; ++i) ur[i] = ug[i * HH + h];

  float* const outrow = out + (size_t)b * SS;
  float* const hfin   = out + (size_t)BB * SS;

  // pack own hv with neighbor-unit hv (quad_perm [2,3,2,3]) and store by 16 lanes
  auto store_h = [&](int par, int l, float hv) __attribute__((always_inline)) {
    float partner = dpp_mov<0xEE>(hv);
    if ((lane & 3) == 0)
      hbuf16[par][l][lane >> 2] = (int)bcu(__builtin_amdgcn_cvt_pkrtz(hv, partner));
  };
  auto ld2 = [&](const int* p, uint4& A, uint4& B) __attribute__((always_inline)) {
    const uint4* q = (const uint4*)p;
    A = q[0]; B = q[1];
  };

  // Verified parity pattern (R4/R6/R7): shared vectors per tick:
  // V0=hbuf[par^1][0] (A0 own + A1 in), V1=hbuf[par][1] (A1 own + A2 in),
  // V2=hbuf[par^1][2] (A2 own + A3 in), V3=hbuf[par][3] (A3 own).
  auto tick = [&](int T, int par, int URI, bool A0, bool A1, bool A2, bool A3)
      __attribute__((always_inline)) {
    uint4 V0a, V0b, V1a, V1b, V2a, V2b, V3a, V3b;
    // ---- read phase: all LDS reads batched up front ----
    if (A0 || A1) ld2(&hbuf16[par ^ 1][0][ks * 8], V0a, V0b);
    if (A1 || A2) ld2(&hbuf16[par][1][ks * 8], V1a, V1b);
    if (A2 || A3) ld2(&hbuf16[par ^ 1][2][ks * 8], V2a, V2b);
    if (A3)       ld2(&hbuf16[par][3][ks * 8], V3a, V3b);
    // ---- compute + write phase ----
    if (A0) {
      float acc = dot16v(w0h, V0a, V0b);
      acc = dpp_add<0xB1>(acc) + ur[URI];  // u0 includes x-part + full bias0
      const float hv = tanh_fast(acc);
      store_h(par, 0, hv);
      if (T == SS - 1 && ks == 0) hfin[(0 * BB + b) * HH + h] = hv;
      int tl = T + 4; tl = (tl < SS) ? tl : (SS - 1);
      ur[URI] = ug[tl * HH + h];  // reload for T+4 (plain load, dep-scheduled)
    }
    if (A1) {
      float acc = dot16v(wi[0], V0a, V0b) + dot16v(wh[0], V1a, V1b);
      acc = dpp_add<0xB1>(acc) + bias[1];
      const float hv = tanh_fast(acc);
      store_h(par ^ 1, 1, hv);
      if (T == SS && ks == 0) hfin[(1 * BB + b) * HH + h] = hv;
    }
    if (A2) {
      float acc = dot16v(wi[1], V1a, V1b) + dot16v(wh[1], V2a, V2b);
      acc = dpp_add<0xB1>(acc) + bias[2];
      const float hv = tanh_fast(acc);
      store_h(par, 2, hv);
      if (T == SS + 1 && ks == 0) hfin[(2 * BB + b) * HH + h] = hv;
    }
    if (A3) {
      float acc = dot16v(wi[2], V2a, V2b) + dot16v(wh[2], V3a, V3b);
      acc = dpp_add<0xB1>(acc) + bias[3];
      const float hv = tanh_fast(acc);
      store_h(par ^ 1, 3, hv);
      const int t3 = T - 3;
      if (t3 == SS - 1 && ks == 0) hfin[(3 * BB + b) * HH + h] = hv;
      // FC reduce via DPP cascade; lane 63 holds the 64-lane sum.
      float v = hv * fcwh;
      v = dpp_add<0x111>(v);  // row_shr:1
      v = dpp_add<0x112>(v);  // row_shr:2
      v = dpp_add<0x114>(v);  // row_shr:4
      v = dpp_add<0x118>(v);  // row_shr:8
      v = dpp_add<0x142>(v);  // row_bcast:15
      v = dpp_add<0x143>(v);  // row_bcast:31
      if (lane == 63) lbuf[t3 & 63] = v + fcb;
      if ((t3 & 63) == 63) {  // coalesced flush of 64 logits
        float lv = lbuf[lane];
        outrow[t3 - 63 + lane] = lv;
      }
    }
  };

  // prologue (layers come online one per tick); URI = T&3
  tick(0, 0, 0, true, false, false, false);
  tick(1, 1, 1, true, true, false, false);
  tick(2, 0, 2, true, true, true, false);
  tick(3, 1, 3, true, true, true, true);
  // steady: unroll-4 so parity AND prefetch-reg index are compile-time
  for (int T = 4; T < SS; T += 4) {
    tick(T,     0, 0, true, true, true, true);
    tick(T + 1, 1, 1, true, true, true, true);
    tick(T + 2, 0, 2, true, true, true, true);
    tick(T + 3, 1, 3, true, true, true, true);
  }
  // drain
  tick(SS,     0, 0, false, true, true, true);
  tick(SS + 1, 1, 1, false, false, true, true);
  tick(SS + 2, 0, 2, false, false, false, true);
}

__global__ __launch_bounds__(256) void softmax_kernel(float* __restrict__ out) {
  __shared__ float red[8];
  const int row = blockIdx.x;
  float* p = out + (size_t)row * SS;
  const int tid = threadIdx.x;
  float4 v = ((const float4*)p)[tid];  // 256 threads x 4 = 1024 logits
  float m = fmaxf(fmaxf(v.x, v.y), fmaxf(v.z, v.w));
#pragma unroll
  for (int d = 32; d >= 1; d >>= 1) m = fmaxf(m, __shfl_xor(m, d));
  if ((tid & 63) == 0) red[tid >> 6] = m;
  __syncthreads();
  m = fmaxf(fmaxf(red[0], red[1]), fmaxf(red[2], red[3]));
  const float e0 = __expf(v.x - m), e1 = __expf(v.y - m);
  const float e2 = __expf(v.z - m), e3 = __expf(v.w - m);
  float s = (e0 + e1) + (e2 + e3);
#pragma unroll
  for (int d = 32; d >= 1; d >>= 1) s += __shfl_xor(s, d);
  if ((tid & 63) == 0) red[4 + (tid >> 6)] = s;
  __syncthreads();
  s = (red[4] + red[5]) + (red[6] + red[7]);
  const float inv = 1.0f / s;
  float4 o;
  o.x = e0 * inv; o.y = e1 * inv; o.z = e2 * inv; o.w = e3 * inv;
  ((float4*)p)[tid] = o;
}

extern "C" void kernel_launch(void* const* d_in, const int* in_sizes, int n_in,
                              void* d_out, int out_size, void* d_ws, size_t ws_size,
                              hipStream_t stream) {
  const float* x         = (const float*)d_in[0];
  const float* h_state   = (const float*)d_in[1];
  const float* W_ih0     = (const float*)d_in[2];
  const float* W_ih_rest = (const float*)d_in[3];
  const float* W_hh      = (const float*)d_in[4];
  const float* b_ih      = (const float*)d_in[5];
  const float* b_hh      = (const float*)d_in[6];
  const float* fc_w      = (const float*)d_in[7];
  const float* fc_b      = (const float*)d_in[8];
  float* out = (float*)d_out;
  float* u0  = (float*)d_ws;  // [B,S,32] fp32 = 67 MB scratch

  hipLaunchKernelGGL(u0_kernel, dim3((BB * SS) / 256), dim3(256), 0, stream,
                     x, W_ih0, b_ih, b_hh, u0);
  hipLaunchKernelGGL(rnn_kernel, dim3(BB), dim3(64), 0, stream,
                     u0, h_state, W_ih_rest, W_hh, b_ih, b_hh, fc_w, fc_b, out);
  hipLaunchKernelGGL(softmax_kernel, dim3(BB), dim3(256), 0, stream, out);
}